// Round 6
// baseline (1643.334 us; speedup 1.0000x reference)
//
#include <hip/hip_runtime.h>
#include <hip/hip_bf16.h>

#define N_NODES 50000
#define N_EDGES 800000
#define NPATH 3
#define NBKT 196                    // ceil(50000/256) buckets per path
#define NBKT3 (NPATH * NBKT)        // 588

typedef __attribute__((ext_vector_type(8))) short short8;
typedef __attribute__((ext_vector_type(4))) float v4f;

// ---------------------------------------------------------------------------
// Pass A: bucket histogram (LDS-aggregated). bucket = p*NBKT + (d>>8).
// ---------------------------------------------------------------------------
__global__ __launch_bounds__(256) void bucket_count_kernel(
    const int* __restrict__ ei, int* __restrict__ bcnt) {
  __shared__ int lcnt[NBKT3];
  const int t = threadIdx.x;
  for (int j = t; j < NBKT3; j += 256) lcnt[j] = 0;
  __syncthreads();
  const int total = NPATH * N_EDGES;
  for (int idx = blockIdx.x * 256 + t; idx < total; idx += gridDim.x * 256) {
    int p = idx / N_EDGES, e = idx - p * N_EDGES;
    int d = ei[p * 2 * N_EDGES + N_EDGES + e];
    atomicAdd(&lcnt[p * NBKT + (d >> 8)], 1);
  }
  __syncthreads();
  for (int j = t; j < NBKT3; j += 256)
    if (lcnt[j]) atomicAdd(&bcnt[j], lcnt[j]);
}

// ---------------------------------------------------------------------------
// Scan over 588 bucket counts (single block). boff = exclusive scan; bcur=boff.
// ---------------------------------------------------------------------------
__global__ __launch_bounds__(1024) void bucket_scan_kernel(
    const int* __restrict__ bcnt, int* __restrict__ boff, int* __restrict__ bcur) {
  __shared__ int tmp[1024];
  const int t = threadIdx.x;
  int v = (t < NBKT3) ? bcnt[t] : 0;
  tmp[t] = v;
  __syncthreads();
  for (int ofs = 1; ofs < 1024; ofs <<= 1) {
    int x = (t >= ofs) ? tmp[t - ofs] : 0;
    __syncthreads();
    tmp[t] += x;
    __syncthreads();
  }
  if (t < NBKT3) {
    int excl = tmp[t] - v;
    boff[t] = excl;
    bcur[t] = excl;
  }
}

// ---------------------------------------------------------------------------
// Pass B: scatter (src,dst) into bucket-ordered ebuf. Per-bucket positions
// are sequential -> 64B lines fill densely (low write amplification).
// ---------------------------------------------------------------------------
__global__ __launch_bounds__(256) void bucket_scatter_kernel(
    const int* __restrict__ ei, int* __restrict__ bcur, int2* __restrict__ ebuf) {
  const int total = NPATH * N_EDGES;
  for (int idx = blockIdx.x * 256 + threadIdx.x; idx < total; idx += gridDim.x * 256) {
    int p = idx / N_EDGES, e = idx - p * N_EDGES;
    int s = ei[p * 2 * N_EDGES + e];
    int d = ei[p * 2 * N_EDGES + N_EDGES + e];
    int pos = atomicAdd(&bcur[p * NBKT + (d >> 8)], 1);
    ebuf[pos] = make_int2(s, d);
  }
}

// ---------------------------------------------------------------------------
// Pass C: per-bucket CSR finalize. One block per bucket; bucket edges are
// contiguous in ebuf. LDS count+scan over the bucket's 256 nodes; write
// off3/deg3 (coalesced, GLOBAL offsets) and csr_src (within ~16KB window).
// ---------------------------------------------------------------------------
__global__ __launch_bounds__(256) void bucket_csr_kernel(
    const int2* __restrict__ ebuf, const int* __restrict__ boff,
    const int* __restrict__ bcnt,
    int* __restrict__ off3, int* __restrict__ deg3, int* __restrict__ csr_src) {
  __shared__ int cnt[256], excl[256], cur[256];
  const int b = blockIdx.x;
  const int t = threadIdx.x;
  const int p = b / NBKT;
  const int node_base = (b - p * NBKT) * 256;
  const int start = boff[b];
  const int ecount = bcnt[b];

  cnt[t] = 0;
  __syncthreads();
  for (int i = t; i < ecount; i += 256)
    atomicAdd(&cnt[ebuf[start + i].y & 255], 1);
  __syncthreads();

  // exclusive scan of cnt[256] (Hillis-Steele on inclusive, then subtract)
  int v = cnt[t];
  excl[t] = v;
  __syncthreads();
  for (int ofs = 1; ofs < 256; ofs <<= 1) {
    int x = (t >= ofs) ? excl[t - ofs] : 0;
    __syncthreads();
    excl[t] += x;
    __syncthreads();
  }
  int my_excl = excl[t] - v;
  cur[t] = my_excl;
  const int node = node_base + t;
  if (node < N_NODES) {
    off3[p * N_NODES + node] = start + my_excl;   // GLOBAL offset
    deg3[p * N_NODES + node] = v;
  }
  __syncthreads();

  for (int i = t; i < ecount; i += 256) {
    int2 e = ebuf[start + i];
    int pos = atomicAdd(&cur[e.y & 255], 1);
    csr_src[start + pos] = e.x;
  }
}

// ---------------------------------------------------------------------------
// h split: h_hi = bf16(h), h_lo = bf16(h - h_hi). Once per launch.
// ---------------------------------------------------------------------------
__global__ __launch_bounds__(256) void hsplit_kernel(
    const float* __restrict__ h,
    __hip_bfloat16* __restrict__ h_hi, __hip_bfloat16* __restrict__ h_lo) {
  int i = blockIdx.x * 256 + threadIdx.x;
  if (i >= N_NODES * 128) return;
  float v = h[i];
  __hip_bfloat16 hb = __float2bfloat16(v);
  h_hi[i] = hb;
  h_lo[i] = __float2bfloat16(v - __bfloat162float(hb));
}

// ---------------------------------------------------------------------------
// Per-path prep 1: Walr[k][c] (128x16): c<8 -> W@al (head c), c>=8 -> W@ar.
// ---------------------------------------------------------------------------
__global__ __launch_bounds__(256) void walr_kernel(
    const float* __restrict__ W, const float* __restrict__ al,
    const float* __restrict__ ar, float* __restrict__ Walr) {
  int idx = blockIdx.x * 256 + threadIdx.x;
  if (idx >= 128 * 16) return;
  int k = idx >> 4, c = idx & 15;
  int h8 = c & 7;
  const float* av = (c < 8) ? al : ar;
  float s = 0.f;
  for (int d = 0; d < 32; d++)
    s = fmaf(W[k * 256 + h8 * 32 + d], av[h8 * 32 + d], s);
  Walr[k * 16 + c] = s;
}

// ---------------------------------------------------------------------------
// Per-path prep 2: W fragments (17 N-tiles; tile 16 = Walr), B-operand order.
// ---------------------------------------------------------------------------
__global__ __launch_bounds__(256) void wfrag_kernel(
    const float* __restrict__ W, const float* __restrict__ Walr,
    __hip_bfloat16* __restrict__ Wf_hi, __hip_bfloat16* __restrict__ Wf_lo) {
  int idx = blockIdx.x * 256 + threadIdx.x;
  if (idx >= 4 * 17 * 64) return;
  int lane = idx & 63;
  int tmp = idx >> 6;            // kc*17 + nt
  int nt = tmp % 17, kc = tmp / 17;
  int l15 = lane & 15, quad = lane >> 4;
  for (int j = 0; j < 8; j++) {
    int k = kc * 32 + quad * 8 + j;
    float v = (nt < 16) ? W[k * 256 + nt * 16 + l15] : Walr[k * 16 + l15];
    __hip_bfloat16 hb = __float2bfloat16(v);
    Wf_hi[(tmp * 64 + lane) * 8 + j] = hb;
    Wf_lo[(tmp * 64 + lane) * 8 + j] = __float2bfloat16(v - __bfloat162float(hb));
  }
}

// ---------------------------------------------------------------------------
// Per-path prep 3: sem_w fragments (8 kc x 8 nt), B-operand order.
// ---------------------------------------------------------------------------
__global__ __launch_bounds__(256) void bsem_kernel(
    const float* __restrict__ Ws,
    __hip_bfloat16* __restrict__ Bs_hi, __hip_bfloat16* __restrict__ Bs_lo) {
  int idx = blockIdx.x * 256 + threadIdx.x;
  if (idx >= 8 * 8 * 64) return;
  int lane = idx & 63;
  int tmp = idx >> 6;            // kc*8 + nt
  int nt = tmp & 7, kc = tmp >> 3;
  int l15 = lane & 15, quad = lane >> 4;
  for (int j = 0; j < 8; j++) {
    int k = kc * 32 + quad * 8 + j;
    float v = Ws[k * 128 + nt * 16 + l15];
    __hip_bfloat16 hb = __float2bfloat16(v);
    Bs_hi[(tmp * 64 + lane) * 8 + j] = hb;
    Bs_lo[(tmp * 64 + lane) * 8 + j] = __float2bfloat16(v - __bfloat162float(hb));
  }
}

// ---------------------------------------------------------------------------
// MFMA 1: feat = h @ W (bf16x3), 17th N-tile = [el|er]. 1 wave / 16 rows.
// ---------------------------------------------------------------------------
__global__ __launch_bounds__(64) void feat_mfma_kernel(
    const __hip_bfloat16* __restrict__ h_hi, const __hip_bfloat16* __restrict__ h_lo,
    const __hip_bfloat16* __restrict__ Wf_hi, const __hip_bfloat16* __restrict__ Wf_lo,
    __hip_bfloat16* __restrict__ feat, float* __restrict__ el, float* __restrict__ er) {
  const int lane = threadIdx.x;
  const int l15 = lane & 15, quad = lane >> 4;
  const int m0 = blockIdx.x * 16;
  const int mrow = m0 + l15;

  v4f acc[17];
#pragma unroll
  for (int nt = 0; nt < 17; nt++) acc[nt] = {0.f, 0.f, 0.f, 0.f};

#pragma unroll
  for (int kc = 0; kc < 4; kc++) {
    short8 ahi = *(const short8*)(h_hi + mrow * 128 + kc * 32 + quad * 8);
    short8 alo = *(const short8*)(h_lo + mrow * 128 + kc * 32 + quad * 8);
#pragma unroll
    for (int nt = 0; nt < 17; nt++) {
      const int o = ((kc * 17 + nt) * 64 + lane) * 8;
      short8 bhi = *(const short8*)(Wf_hi + o);
      short8 blo = *(const short8*)(Wf_lo + o);
      acc[nt] = __builtin_amdgcn_mfma_f32_16x16x32_bf16(ahi, bhi, acc[nt], 0, 0, 0);
      acc[nt] = __builtin_amdgcn_mfma_f32_16x16x32_bf16(ahi, blo, acc[nt], 0, 0, 0);
      acc[nt] = __builtin_amdgcn_mfma_f32_16x16x32_bf16(alo, bhi, acc[nt], 0, 0, 0);
    }
  }

#pragma unroll
  for (int nt = 0; nt < 16; nt++)
#pragma unroll
    for (int r = 0; r < 4; r++) {
      int m = m0 + quad * 4 + r;
      feat[(size_t)m * 256 + nt * 16 + l15] = __float2bfloat16(acc[nt][r]);
    }
#pragma unroll
  for (int r = 0; r < 4; r++) {
    int m = m0 + quad * 4 + r;
    float v = acc[16][r];
    if (l15 < 8) el[m * 8 + l15] = v;
    else         er[m * 8 + (l15 - 8)] = v;
  }
}

// ---------------------------------------------------------------------------
// Aggregate: per-dst gather, fused softmax+elu; writes eagg hi/lo split.
// ---------------------------------------------------------------------------
__global__ __launch_bounds__(256) void aggregate_kernel(
    const int* __restrict__ csr_src, const int* __restrict__ off,
    const int* __restrict__ deg,
    const float* __restrict__ el, const float* __restrict__ er,
    const __hip_bfloat16* __restrict__ feat,
    __hip_bfloat16* __restrict__ eagg_hi, __hip_bfloat16* __restrict__ eagg_lo) {
  const int d = blockIdx.x;
  const int t = threadIdx.x;
  const int h = t >> 5;
  const float erh = er[d * 8 + h];
  const int start = off[d];
  const int n = deg[d];
  const int* lst = csr_src + start;

  float accN = 0.f, accD = 0.f;
  int j = 0;
  for (; j + 4 <= n; j += 4) {
    int s0 = lst[j + 0], s1 = lst[j + 1], s2 = lst[j + 2], s3 = lst[j + 3];
    float x0 = el[s0 * 8 + h] + erh;
    float x1 = el[s1 * 8 + h] + erh;
    float x2 = el[s2 * 8 + h] + erh;
    float x3 = el[s3 * 8 + h] + erh;
    float v0 = __bfloat162float(feat[(size_t)s0 * 256 + t]);
    float v1 = __bfloat162float(feat[(size_t)s1 * 256 + t]);
    float v2 = __bfloat162float(feat[(size_t)s2 * 256 + t]);
    float v3 = __bfloat162float(feat[(size_t)s3 * 256 + t]);
    x0 = x0 > 0.f ? x0 : 0.2f * x0;  float e0 = __expf(x0);
    x1 = x1 > 0.f ? x1 : 0.2f * x1;  float e1 = __expf(x1);
    x2 = x2 > 0.f ? x2 : 0.2f * x2;  float e2 = __expf(x2);
    x3 = x3 > 0.f ? x3 : 0.2f * x3;  float e3 = __expf(x3);
    accN = fmaf(e0, v0, accN);  accD += e0;
    accN = fmaf(e1, v1, accN);  accD += e1;
    accN = fmaf(e2, v2, accN);  accD += e2;
    accN = fmaf(e3, v3, accN);  accD += e3;
  }
  for (; j < n; j++) {
    int s = lst[j];
    float x = el[s * 8 + h] + erh;
    x = x > 0.f ? x : 0.2f * x;
    float ex = __expf(x);
    accN = fmaf(ex, __bfloat162float(feat[(size_t)s * 256 + t]), accN);
    accD += ex;
  }

  float r = (n > 0) ? accN / accD : 0.f;
  r = r > 0.f ? r : (__expf(r) - 1.f);
  __hip_bfloat16 hb = __float2bfloat16(r);
  eagg_hi[(size_t)d * 256 + t] = hb;
  eagg_lo[(size_t)d * 256 + t] = __float2bfloat16(r - __bfloat162float(hb));
}

// ---------------------------------------------------------------------------
// MFMA 2: out (+)= eagg @ sem_w (bf16x3). mode 0: init with bias.
// ---------------------------------------------------------------------------
__global__ __launch_bounds__(64) void sem_mfma_kernel(
    const __hip_bfloat16* __restrict__ eagg_hi, const __hip_bfloat16* __restrict__ eagg_lo,
    const __hip_bfloat16* __restrict__ Bs_hi, const __hip_bfloat16* __restrict__ Bs_lo,
    const float* __restrict__ bias, float* __restrict__ out, int mode) {
  const int lane = threadIdx.x;
  const int l15 = lane & 15, quad = lane >> 4;
  const int m0 = blockIdx.x * 16;
  const int mrow = m0 + l15;

  v4f acc[8];
#pragma unroll
  for (int nt = 0; nt < 8; nt++) acc[nt] = {0.f, 0.f, 0.f, 0.f};

#pragma unroll
  for (int kc = 0; kc < 8; kc++) {
    short8 ahi = *(const short8*)(eagg_hi + (size_t)mrow * 256 + kc * 32 + quad * 8);
    short8 alo = *(const short8*)(eagg_lo + (size_t)mrow * 256 + kc * 32 + quad * 8);
#pragma unroll
    for (int nt = 0; nt < 8; nt++) {
      const int o = ((kc * 8 + nt) * 64 + lane) * 8;
      short8 bhi = *(const short8*)(Bs_hi + o);
      short8 blo = *(const short8*)(Bs_lo + o);
      acc[nt] = __builtin_amdgcn_mfma_f32_16x16x32_bf16(ahi, bhi, acc[nt], 0, 0, 0);
      acc[nt] = __builtin_amdgcn_mfma_f32_16x16x32_bf16(ahi, blo, acc[nt], 0, 0, 0);
      acc[nt] = __builtin_amdgcn_mfma_f32_16x16x32_bf16(alo, bhi, acc[nt], 0, 0, 0);
    }
  }

#pragma unroll
  for (int nt = 0; nt < 8; nt++)
#pragma unroll
    for (int r = 0; r < 4; r++) {
      int m = m0 + quad * 4 + r;
      size_t o = (size_t)m * 128 + nt * 16 + l15;
      float v = acc[nt][r];
      if (mode == 0) v += bias[nt * 16 + l15];
      else           v += out[o];
      out[o] = v;
    }
}

// ---------------------------------------------------------------------------
extern "C" void kernel_launch(void* const* d_in, const int* in_sizes, int n_in,
                              void* d_out, int out_size, void* d_ws, size_t ws_size,
                              hipStream_t stream) {
  const float* h      = (const float*)d_in[0];
  const int*   ei     = (const int*)d_in[1];
  const float* fc_w   = (const float*)d_in[2];
  const float* attn_l = (const float*)d_in[3];
  const float* attn_r = (const float*)d_in[4];
  const float* sem_w  = (const float*)d_in[5];
  const float* sem_b  = (const float*)d_in[6];
  float* out = (float*)d_out;

  // workspace layout (bytes) — total ~117.5 MB (<=132.8 MB proven safe)
  // ebuf (19.2 MB) time-shares the eagg region: used only in CSR build
  // (before any aggregate in the same launch).
  char* ws = (char*)d_ws;
  __hip_bfloat16* h_hi    = (__hip_bfloat16*)ws;                   // 12.8 MB
  __hip_bfloat16* h_lo    = (__hip_bfloat16*)(ws + 12800000);      // 12.8 MB
  __hip_bfloat16* feat    = (__hip_bfloat16*)(ws + 25600000);      // 25.6 MB
  int2*           ebuf    = (int2*)(ws + 51200000);                // 19.2 MB (union)
  __hip_bfloat16* eagg_hi = (__hip_bfloat16*)(ws + 51200000);      // 25.6 MB (union)
  __hip_bfloat16* eagg_lo = (__hip_bfloat16*)(ws + 76800000);      // 25.6 MB
  float* el      = (float*)(ws + 102400000);                       // 1.6 MB
  float* er      = (float*)(ws + 104000000);                       // 1.6 MB
  int*   deg3    = (int*)(ws + 105600000);                         // 0.6 MB
  int*   off3    = (int*)(ws + 106200000);                         // 0.6 MB
  int*   bcnt    = (int*)(ws + 106800000);                         // 2.4 KB
  int*   boff    = (int*)(ws + 106810000);                         // 2.4 KB
  int*   bcur    = (int*)(ws + 106820000);                         // 2.4 KB
  int*   csr_src = (int*)(ws + 107400000);                         // 9.6 MB
  __hip_bfloat16* Wf_hi   = (__hip_bfloat16*)(ws + 117000000);     // 68 KB
  __hip_bfloat16* Wf_lo   = (__hip_bfloat16*)(ws + 117100000);     // 68 KB
  float*          Walr    = (float*)(ws + 117200000);              // 8 KB
  __hip_bfloat16* Bs_hi   = (__hip_bfloat16*)(ws + 117300000);     // 64 KB
  __hip_bfloat16* Bs_lo   = (__hip_bfloat16*)(ws + 117400000);     // 64 KB

  // --- CSR build (bucketed, low write-amplification) + h split ---
  hipMemsetAsync(bcnt, 0, NBKT3 * sizeof(int), stream);
  bucket_count_kernel<<<1024, 256, 0, stream>>>(ei, bcnt);
  bucket_scan_kernel<<<1, 1024, 0, stream>>>(bcnt, boff, bcur);
  bucket_scatter_kernel<<<1024, 256, 0, stream>>>(ei, bcur, ebuf);
  bucket_csr_kernel<<<NBKT3, 256, 0, stream>>>(ebuf, boff, bcnt, off3, deg3, csr_src);
  hsplit_kernel<<<(N_NODES * 128 + 255) / 256, 256, 0, stream>>>(h, h_hi, h_lo);

  for (int p = 0; p < NPATH; p++) {
    const float* W  = fc_w + (size_t)p * 128 * 256;
    const float* Ws = sem_w + (size_t)p * 256 * 128;

    walr_kernel<<<8, 256, 0, stream>>>(W, attn_l + p * 256, attn_r + p * 256, Walr);
    wfrag_kernel<<<17, 256, 0, stream>>>(W, Walr, Wf_hi, Wf_lo);
    bsem_kernel<<<16, 256, 0, stream>>>(Ws, Bs_hi, Bs_lo);

    feat_mfma_kernel<<<N_NODES / 16, 64, 0, stream>>>(
        h_hi, h_lo, Wf_hi, Wf_lo, feat, el, er);
    // off3 holds GLOBAL csr offsets (across paths) -> pass csr_src base.
    aggregate_kernel<<<N_NODES, 256, 0, stream>>>(
        csr_src, off3 + p * N_NODES, deg3 + p * N_NODES,
        el, er, feat, eagg_hi, eagg_lo);
    sem_mfma_kernel<<<N_NODES / 16, 64, 0, stream>>>(
        eagg_hi, eagg_lo, Bs_hi, Bs_lo, sem_b, out, p);
  }
}

// Round 7
// 656.905 us; speedup vs baseline: 2.5016x; 2.5016x over previous
//
#include <hip/hip_runtime.h>
#include <hip/hip_bf16.h>

#define N_NODES 50000
#define N_EDGES 800000
#define NPATH 3
#define NBKT 196                    // ceil(50000/256) buckets per path
#define NBKT3 (NPATH * NBKT)        // 588
#define NCHUNKBLK 256               // blocks for count/scatter passes
#define CHUNK 9375                  // (3*800000)/256 exact

typedef __attribute__((ext_vector_type(8))) short short8;
typedef __attribute__((ext_vector_type(4))) float v4f;

// ---------------------------------------------------------------------------
// Pass A: per-block LDS histogram of bucket membership. NO global atomics.
// Block blk handles edges [blk*CHUNK, (blk+1)*CHUNK).
// ---------------------------------------------------------------------------
__global__ __launch_bounds__(256) void blk_count_kernel(
    const int* __restrict__ ei, int* __restrict__ cntmat) {
  __shared__ int lcnt[NBKT3];
  const int t = threadIdx.x, blk = blockIdx.x;
  for (int j = t; j < NBKT3; j += 256) lcnt[j] = 0;
  __syncthreads();
  const int lo = blk * CHUNK, hi = lo + CHUNK;
  for (int idx = lo + t; idx < hi; idx += 256) {
    int p = idx / N_EDGES, e = idx - p * N_EDGES;
    int d = ei[p * 2 * N_EDGES + N_EDGES + e];
    atomicAdd(&lcnt[p * NBKT + (d >> 8)], 1);   // LDS atomic
  }
  __syncthreads();
  for (int j = t; j < NBKT3; j += 256) cntmat[blk * NBKT3 + j] = lcnt[j];
}

// ---------------------------------------------------------------------------
// Pass B: per-bucket scan across the 256 block-counts.
// pos[b][blk] = exclusive prefix; btot[b] = bucket total.
// ---------------------------------------------------------------------------
__global__ __launch_bounds__(256) void col_scan_kernel(
    const int* __restrict__ cntmat, int* __restrict__ pos, int* __restrict__ btot) {
  __shared__ int tmp[256];
  const int b = blockIdx.x, t = threadIdx.x;
  int v = cntmat[t * NBKT3 + b];
  tmp[t] = v;
  __syncthreads();
  for (int ofs = 1; ofs < 256; ofs <<= 1) {
    int x = (t >= ofs) ? tmp[t - ofs] : 0;
    __syncthreads();
    tmp[t] += x;
    __syncthreads();
  }
  pos[b * 256 + t] = tmp[t] - v;
  if (t == 255) btot[b] = tmp[255];
}

// ---------------------------------------------------------------------------
// Pass C: exclusive scan over the 588 bucket totals (single block).
// ---------------------------------------------------------------------------
__global__ __launch_bounds__(1024) void bucket_scan_kernel(
    const int* __restrict__ btot, int* __restrict__ boff) {
  __shared__ int tmp[1024];
  const int t = threadIdx.x;
  int v = (t < NBKT3) ? btot[t] : 0;
  tmp[t] = v;
  __syncthreads();
  for (int ofs = 1; ofs < 1024; ofs <<= 1) {
    int x = (t >= ofs) ? tmp[t - ofs] : 0;
    __syncthreads();
    tmp[t] += x;
    __syncthreads();
  }
  if (t < NBKT3) boff[t] = tmp[t] - v;
}

// ---------------------------------------------------------------------------
// Pass D: deterministic scatter. LDS cursors seeded with boff[b]+pos[b][blk];
// positions are globally disjoint & dense. NO global atomics.
// ---------------------------------------------------------------------------
__global__ __launch_bounds__(256) void scatter_det_kernel(
    const int* __restrict__ ei, const int* __restrict__ boff,
    const int* __restrict__ pos, int2* __restrict__ ebuf) {
  __shared__ int cursor[NBKT3];
  const int t = threadIdx.x, blk = blockIdx.x;
  for (int j = t; j < NBKT3; j += 256)
    cursor[j] = boff[j] + pos[j * 256 + blk];
  __syncthreads();
  const int lo = blk * CHUNK, hi = lo + CHUNK;
  for (int idx = lo + t; idx < hi; idx += 256) {
    int p = idx / N_EDGES, e = idx - p * N_EDGES;
    int s = ei[p * 2 * N_EDGES + e];
    int d = ei[p * 2 * N_EDGES + N_EDGES + e];
    int ps = atomicAdd(&cursor[p * NBKT + (d >> 8)], 1);   // LDS atomic
    ebuf[ps] = make_int2(s, d);
  }
}

// ---------------------------------------------------------------------------
// Pass E: per-bucket CSR finalize (unchanged from R6 — was never a hotspot).
// ---------------------------------------------------------------------------
__global__ __launch_bounds__(256) void bucket_csr_kernel(
    const int2* __restrict__ ebuf, const int* __restrict__ boff,
    const int* __restrict__ btot,
    int* __restrict__ off3, int* __restrict__ deg3, int* __restrict__ csr_src) {
  __shared__ int cnt[256], excl[256], cur[256];
  const int b = blockIdx.x;
  const int t = threadIdx.x;
  const int p = b / NBKT;
  const int node_base = (b - p * NBKT) * 256;
  const int start = boff[b];
  const int ecount = btot[b];

  cnt[t] = 0;
  __syncthreads();
  for (int i = t; i < ecount; i += 256)
    atomicAdd(&cnt[ebuf[start + i].y & 255], 1);
  __syncthreads();

  int v = cnt[t];
  excl[t] = v;
  __syncthreads();
  for (int ofs = 1; ofs < 256; ofs <<= 1) {
    int x = (t >= ofs) ? excl[t - ofs] : 0;
    __syncthreads();
    excl[t] += x;
    __syncthreads();
  }
  int my_excl = excl[t] - v;
  cur[t] = my_excl;
  const int node = node_base + t;
  if (node < N_NODES) {
    off3[p * N_NODES + node] = start + my_excl;   // GLOBAL offset
    deg3[p * N_NODES + node] = v;
  }
  __syncthreads();

  for (int i = t; i < ecount; i += 256) {
    int2 e = ebuf[start + i];
    int pos2 = atomicAdd(&cur[e.y & 255], 1);
    csr_src[start + pos2] = e.x;
  }
}

// ---------------------------------------------------------------------------
// h split: h_hi = bf16(h), h_lo = bf16(h - h_hi). Once per launch.
// ---------------------------------------------------------------------------
__global__ __launch_bounds__(256) void hsplit_kernel(
    const float* __restrict__ h,
    __hip_bfloat16* __restrict__ h_hi, __hip_bfloat16* __restrict__ h_lo) {
  int i = blockIdx.x * 256 + threadIdx.x;
  if (i >= N_NODES * 128) return;
  float v = h[i];
  __hip_bfloat16 hb = __float2bfloat16(v);
  h_hi[i] = hb;
  h_lo[i] = __float2bfloat16(v - __bfloat162float(hb));
}

// ---------------------------------------------------------------------------
// Per-path prep 1: Walr[k][c] (128x16): c<8 -> W@al (head c), c>=8 -> W@ar.
// ---------------------------------------------------------------------------
__global__ __launch_bounds__(256) void walr_kernel(
    const float* __restrict__ W, const float* __restrict__ al,
    const float* __restrict__ ar, float* __restrict__ Walr) {
  int idx = blockIdx.x * 256 + threadIdx.x;
  if (idx >= 128 * 16) return;
  int k = idx >> 4, c = idx & 15;
  int h8 = c & 7;
  const float* av = (c < 8) ? al : ar;
  float s = 0.f;
  for (int d = 0; d < 32; d++)
    s = fmaf(W[k * 256 + h8 * 32 + d], av[h8 * 32 + d], s);
  Walr[k * 16 + c] = s;
}

// ---------------------------------------------------------------------------
// Per-path prep 2: W fragments (17 N-tiles; tile 16 = Walr), B-operand order.
// ---------------------------------------------------------------------------
__global__ __launch_bounds__(256) void wfrag_kernel(
    const float* __restrict__ W, const float* __restrict__ Walr,
    __hip_bfloat16* __restrict__ Wf_hi, __hip_bfloat16* __restrict__ Wf_lo) {
  int idx = blockIdx.x * 256 + threadIdx.x;
  if (idx >= 4 * 17 * 64) return;
  int lane = idx & 63;
  int tmp = idx >> 6;            // kc*17 + nt
  int nt = tmp % 17, kc = tmp / 17;
  int l15 = lane & 15, quad = lane >> 4;
  for (int j = 0; j < 8; j++) {
    int k = kc * 32 + quad * 8 + j;
    float v = (nt < 16) ? W[k * 256 + nt * 16 + l15] : Walr[k * 16 + l15];
    __hip_bfloat16 hb = __float2bfloat16(v);
    Wf_hi[(tmp * 64 + lane) * 8 + j] = hb;
    Wf_lo[(tmp * 64 + lane) * 8 + j] = __float2bfloat16(v - __bfloat162float(hb));
  }
}

// ---------------------------------------------------------------------------
// Per-path prep 3: sem_w fragments (8 kc x 8 nt), B-operand order.
// ---------------------------------------------------------------------------
__global__ __launch_bounds__(256) void bsem_kernel(
    const float* __restrict__ Ws,
    __hip_bfloat16* __restrict__ Bs_hi, __hip_bfloat16* __restrict__ Bs_lo) {
  int idx = blockIdx.x * 256 + threadIdx.x;
  if (idx >= 8 * 8 * 64) return;
  int lane = idx & 63;
  int tmp = idx >> 6;            // kc*8 + nt
  int nt = tmp & 7, kc = tmp >> 3;
  int l15 = lane & 15, quad = lane >> 4;
  for (int j = 0; j < 8; j++) {
    int k = kc * 32 + quad * 8 + j;
    float v = Ws[k * 128 + nt * 16 + l15];
    __hip_bfloat16 hb = __float2bfloat16(v);
    Bs_hi[(tmp * 64 + lane) * 8 + j] = hb;
    Bs_lo[(tmp * 64 + lane) * 8 + j] = __float2bfloat16(v - __bfloat162float(hb));
  }
}

// ---------------------------------------------------------------------------
// MFMA 1: feat = h @ W (bf16x3), 17th N-tile = [el|er]. 1 wave / 16 rows.
// ---------------------------------------------------------------------------
__global__ __launch_bounds__(64) void feat_mfma_kernel(
    const __hip_bfloat16* __restrict__ h_hi, const __hip_bfloat16* __restrict__ h_lo,
    const __hip_bfloat16* __restrict__ Wf_hi, const __hip_bfloat16* __restrict__ Wf_lo,
    __hip_bfloat16* __restrict__ feat, float* __restrict__ el, float* __restrict__ er) {
  const int lane = threadIdx.x;
  const int l15 = lane & 15, quad = lane >> 4;
  const int m0 = blockIdx.x * 16;
  const int mrow = m0 + l15;

  v4f acc[17];
#pragma unroll
  for (int nt = 0; nt < 17; nt++) acc[nt] = {0.f, 0.f, 0.f, 0.f};

#pragma unroll
  for (int kc = 0; kc < 4; kc++) {
    short8 ahi = *(const short8*)(h_hi + mrow * 128 + kc * 32 + quad * 8);
    short8 alo = *(const short8*)(h_lo + mrow * 128 + kc * 32 + quad * 8);
#pragma unroll
    for (int nt = 0; nt < 17; nt++) {
      const int o = ((kc * 17 + nt) * 64 + lane) * 8;
      short8 bhi = *(const short8*)(Wf_hi + o);
      short8 blo = *(const short8*)(Wf_lo + o);
      acc[nt] = __builtin_amdgcn_mfma_f32_16x16x32_bf16(ahi, bhi, acc[nt], 0, 0, 0);
      acc[nt] = __builtin_amdgcn_mfma_f32_16x16x32_bf16(ahi, blo, acc[nt], 0, 0, 0);
      acc[nt] = __builtin_amdgcn_mfma_f32_16x16x32_bf16(alo, bhi, acc[nt], 0, 0, 0);
    }
  }

#pragma unroll
  for (int nt = 0; nt < 16; nt++)
#pragma unroll
    for (int r = 0; r < 4; r++) {
      int m = m0 + quad * 4 + r;
      feat[(size_t)m * 256 + nt * 16 + l15] = __float2bfloat16(acc[nt][r]);
    }
#pragma unroll
  for (int r = 0; r < 4; r++) {
    int m = m0 + quad * 4 + r;
    float v = acc[16][r];
    if (l15 < 8) el[m * 8 + l15] = v;
    else         er[m * 8 + (l15 - 8)] = v;
  }
}

// ---------------------------------------------------------------------------
// Aggregate: per-dst gather, fused softmax+elu; writes eagg hi/lo split.
// ---------------------------------------------------------------------------
__global__ __launch_bounds__(256) void aggregate_kernel(
    const int* __restrict__ csr_src, const int* __restrict__ off,
    const int* __restrict__ deg,
    const float* __restrict__ el, const float* __restrict__ er,
    const __hip_bfloat16* __restrict__ feat,
    __hip_bfloat16* __restrict__ eagg_hi, __hip_bfloat16* __restrict__ eagg_lo) {
  const int d = blockIdx.x;
  const int t = threadIdx.x;
  const int h = t >> 5;
  const float erh = er[d * 8 + h];
  const int start = off[d];
  const int n = deg[d];
  const int* lst = csr_src + start;

  float accN = 0.f, accD = 0.f;
  int j = 0;
  for (; j + 4 <= n; j += 4) {
    int s0 = lst[j + 0], s1 = lst[j + 1], s2 = lst[j + 2], s3 = lst[j + 3];
    float x0 = el[s0 * 8 + h] + erh;
    float x1 = el[s1 * 8 + h] + erh;
    float x2 = el[s2 * 8 + h] + erh;
    float x3 = el[s3 * 8 + h] + erh;
    float v0 = __bfloat162float(feat[(size_t)s0 * 256 + t]);
    float v1 = __bfloat162float(feat[(size_t)s1 * 256 + t]);
    float v2 = __bfloat162float(feat[(size_t)s2 * 256 + t]);
    float v3 = __bfloat162float(feat[(size_t)s3 * 256 + t]);
    x0 = x0 > 0.f ? x0 : 0.2f * x0;  float e0 = __expf(x0);
    x1 = x1 > 0.f ? x1 : 0.2f * x1;  float e1 = __expf(x1);
    x2 = x2 > 0.f ? x2 : 0.2f * x2;  float e2 = __expf(x2);
    x3 = x3 > 0.f ? x3 : 0.2f * x3;  float e3 = __expf(x3);
    accN = fmaf(e0, v0, accN);  accD += e0;
    accN = fmaf(e1, v1, accN);  accD += e1;
    accN = fmaf(e2, v2, accN);  accD += e2;
    accN = fmaf(e3, v3, accN);  accD += e3;
  }
  for (; j < n; j++) {
    int s = lst[j];
    float x = el[s * 8 + h] + erh;
    x = x > 0.f ? x : 0.2f * x;
    float ex = __expf(x);
    accN = fmaf(ex, __bfloat162float(feat[(size_t)s * 256 + t]), accN);
    accD += ex;
  }

  float r = (n > 0) ? accN / accD : 0.f;
  r = r > 0.f ? r : (__expf(r) - 1.f);
  __hip_bfloat16 hb = __float2bfloat16(r);
  eagg_hi[(size_t)d * 256 + t] = hb;
  eagg_lo[(size_t)d * 256 + t] = __float2bfloat16(r - __bfloat162float(hb));
}

// ---------------------------------------------------------------------------
// MFMA 2: out (+)= eagg @ sem_w (bf16x3). mode 0: init with bias.
// ---------------------------------------------------------------------------
__global__ __launch_bounds__(64) void sem_mfma_kernel(
    const __hip_bfloat16* __restrict__ eagg_hi, const __hip_bfloat16* __restrict__ eagg_lo,
    const __hip_bfloat16* __restrict__ Bs_hi, const __hip_bfloat16* __restrict__ Bs_lo,
    const float* __restrict__ bias, float* __restrict__ out, int mode) {
  const int lane = threadIdx.x;
  const int l15 = lane & 15, quad = lane >> 4;
  const int m0 = blockIdx.x * 16;
  const int mrow = m0 + l15;

  v4f acc[8];
#pragma unroll
  for (int nt = 0; nt < 8; nt++) acc[nt] = {0.f, 0.f, 0.f, 0.f};

#pragma unroll
  for (int kc = 0; kc < 8; kc++) {
    short8 ahi = *(const short8*)(eagg_hi + (size_t)mrow * 256 + kc * 32 + quad * 8);
    short8 alo = *(const short8*)(eagg_lo + (size_t)mrow * 256 + kc * 32 + quad * 8);
#pragma unroll
    for (int nt = 0; nt < 8; nt++) {
      const int o = ((kc * 8 + nt) * 64 + lane) * 8;
      short8 bhi = *(const short8*)(Bs_hi + o);
      short8 blo = *(const short8*)(Bs_lo + o);
      acc[nt] = __builtin_amdgcn_mfma_f32_16x16x32_bf16(ahi, bhi, acc[nt], 0, 0, 0);
      acc[nt] = __builtin_amdgcn_mfma_f32_16x16x32_bf16(ahi, blo, acc[nt], 0, 0, 0);
      acc[nt] = __builtin_amdgcn_mfma_f32_16x16x32_bf16(alo, bhi, acc[nt], 0, 0, 0);
    }
  }

#pragma unroll
  for (int nt = 0; nt < 8; nt++)
#pragma unroll
    for (int r = 0; r < 4; r++) {
      int m = m0 + quad * 4 + r;
      size_t o = (size_t)m * 128 + nt * 16 + l15;
      float v = acc[nt][r];
      if (mode == 0) v += bias[nt * 16 + l15];
      else           v += out[o];
      out[o] = v;
    }
}

// ---------------------------------------------------------------------------
extern "C" void kernel_launch(void* const* d_in, const int* in_sizes, int n_in,
                              void* d_out, int out_size, void* d_ws, size_t ws_size,
                              hipStream_t stream) {
  const float* h      = (const float*)d_in[0];
  const int*   ei     = (const int*)d_in[1];
  const float* fc_w   = (const float*)d_in[2];
  const float* attn_l = (const float*)d_in[3];
  const float* attn_r = (const float*)d_in[4];
  const float* sem_w  = (const float*)d_in[5];
  const float* sem_b  = (const float*)d_in[6];
  float* out = (float*)d_out;

  // workspace layout (bytes) — total ~119.5 MB (<=132.8 MB proven safe)
  // ebuf (19.2 MB) time-shares the eagg region (used only before aggregate).
  char* ws = (char*)d_ws;
  __hip_bfloat16* h_hi    = (__hip_bfloat16*)ws;                   // 12.8 MB
  __hip_bfloat16* h_lo    = (__hip_bfloat16*)(ws + 12800000);      // 12.8 MB
  __hip_bfloat16* feat    = (__hip_bfloat16*)(ws + 25600000);      // 25.6 MB
  int2*           ebuf    = (int2*)(ws + 51200000);                // 19.2 MB (union)
  __hip_bfloat16* eagg_hi = (__hip_bfloat16*)(ws + 51200000);      // 25.6 MB (union)
  __hip_bfloat16* eagg_lo = (__hip_bfloat16*)(ws + 76800000);      // 25.6 MB
  float* el      = (float*)(ws + 102400000);                       // 1.6 MB
  float* er      = (float*)(ws + 104000000);                       // 1.6 MB
  int*   deg3    = (int*)(ws + 105600000);                         // 0.6 MB
  int*   off3    = (int*)(ws + 106200000);                         // 0.6 MB
  int*   csr_src = (int*)(ws + 107400000);                         // 9.6 MB
  __hip_bfloat16* Wf_hi   = (__hip_bfloat16*)(ws + 117000000);     // 68 KB
  __hip_bfloat16* Wf_lo   = (__hip_bfloat16*)(ws + 117100000);     // 68 KB
  float*          Walr    = (float*)(ws + 117200000);              // 8 KB
  __hip_bfloat16* Bs_hi   = (__hip_bfloat16*)(ws + 117300000);     // 64 KB
  __hip_bfloat16* Bs_lo   = (__hip_bfloat16*)(ws + 117400000);     // 64 KB
  int*   cntmat  = (int*)(ws + 117500000);                         // 602 KB
  int*   posm    = (int*)(ws + 118150000);                         // 602 KB
  int*   btot    = (int*)(ws + 118800000);                         // 2.4 KB
  int*   boff    = (int*)(ws + 118810000);                         // 2.4 KB

  // --- CSR build: deterministic two-level counting sort (zero global atomics)
  blk_count_kernel<<<NCHUNKBLK, 256, 0, stream>>>(ei, cntmat);
  col_scan_kernel<<<NBKT3, 256, 0, stream>>>(cntmat, posm, btot);
  bucket_scan_kernel<<<1, 1024, 0, stream>>>(btot, boff);
  scatter_det_kernel<<<NCHUNKBLK, 256, 0, stream>>>(ei, boff, posm, ebuf);
  bucket_csr_kernel<<<NBKT3, 256, 0, stream>>>(ebuf, boff, btot, off3, deg3, csr_src);
  hsplit_kernel<<<(N_NODES * 128 + 255) / 256, 256, 0, stream>>>(h, h_hi, h_lo);

  for (int p = 0; p < NPATH; p++) {
    const float* W  = fc_w + (size_t)p * 128 * 256;
    const float* Ws = sem_w + (size_t)p * 256 * 128;

    walr_kernel<<<8, 256, 0, stream>>>(W, attn_l + p * 256, attn_r + p * 256, Walr);
    wfrag_kernel<<<17, 256, 0, stream>>>(W, Walr, Wf_hi, Wf_lo);
    bsem_kernel<<<16, 256, 0, stream>>>(Ws, Bs_hi, Bs_lo);

    feat_mfma_kernel<<<N_NODES / 16, 64, 0, stream>>>(
        h_hi, h_lo, Wf_hi, Wf_lo, feat, el, er);
    aggregate_kernel<<<N_NODES, 256, 0, stream>>>(
        csr_src, off3 + p * N_NODES, deg3 + p * N_NODES,
        el, er, feat, eagg_hi, eagg_lo);
    sem_mfma_kernel<<<N_NODES / 16, 64, 0, stream>>>(
        eagg_hi, eagg_lo, Bs_hi, Bs_lo, sem_b, out, p);
  }
}